// Round 7
// baseline (485.535 us; speedup 1.0000x reference)
//
#include <hip/hip_runtime.h>
#include <stdint.h>

typedef short short8 __attribute__((ext_vector_type(8)));
typedef float floatx4 __attribute__((ext_vector_type(4)));

#define BK 256   // nodes per bucket

static __device__ __forceinline__ float bflo(unsigned int u) {
    union { unsigned int i; float f; } v; v.i = u << 16; return v.f;
}
static __device__ __forceinline__ float bfhi(unsigned int u) {
    union { unsigned int i; float f; } v; v.i = u & 0xffff0000u; return v.f;
}
static __device__ __forceinline__ unsigned short f2bf(float f) {
    union { float f; unsigned int i; } v; v.f = f;
    unsigned int u = v.i;
    unsigned int r = u + 0x7fffu + ((u >> 16) & 1u);
    return (unsigned short)(r >> 16);
}

// ---------------- CSR build (r3-proven chain; zero_cnt merged into wconv) ----------------
// r4 lesson: grid.sync ~50us/sync on MI355X -> multi-launch. r6 lesson: last-block
// hist+scan merge cost ~10us -> split hist/scanK restored.

__global__ void k_wconv_all(const float* __restrict__ W1, const float* __restrict__ W2,
                            const float* __restrict__ Wf, unsigned short* __restrict__ wb1,
                            unsigned short* __restrict__ wb2, unsigned short* __restrict__ wbf,
                            int* __restrict__ bucket_cnt) {
    int i = blockIdx.x * 256 + threadIdx.x;
    if (i < 512) bucket_cnt[i] = 0;
    if (i < 16384) {
        int k = i >> 7, n = i & 127;
        wb1[n * 128 + k] = f2bf(W1[i]);
    } else if (i < 32768) {
        int j = i - 16384, k = j >> 7, n = j & 127;
        wb2[n * 128 + k] = f2bf(W2[j]);
    } else if (i < 40960) {
        int j = i - 32768, k = j >> 6, n = j & 63;
        wbf[n * 128 + k] = f2bf(Wf[j]);
    }
}

__global__ __launch_bounds__(256) void k_hist(const int* __restrict__ dst, int* bucket_cnt,
                                              int E, int N, int K) {
    __shared__ int h[4][512];
    int t = threadIdx.x, w = t >> 6;
    for (int i = t; i < 4 * 512; i += 256) ((int*)h)[i] = 0;
    __syncthreads();
    int per = (E + gridDim.x - 1) / gridDim.x;
    int lo = blockIdx.x * per, hi = min(lo + per, E);
    for (int e = lo + t; e < hi; e += 256) {
        unsigned int d = (unsigned int)dst[e];
        if (d < (unsigned int)N) atomicAdd(&h[w][d >> 8], 1);
    }
    __syncthreads();
    for (int i = t; i < K; i += 256) {
        int c = h[0][i] + h[1][i] + h[2][i] + h[3][i];
        if (c) atomicAdd(&bucket_cnt[i], c);
    }
}

__global__ void k_scanK(const int* __restrict__ bucket_cnt, int* bucket_off, int* bucket_cur,
                        int* row_start, int K, int N) {
    __shared__ int s[512];
    int t = threadIdx.x;
    int v = (t < K) ? bucket_cnt[t] : 0;
    s[t] = v; __syncthreads();
    for (int off = 1; off < 512; off <<= 1) {
        int x = (t >= off) ? s[t - off] : 0;
        __syncthreads();
        s[t] += x;
        __syncthreads();
    }
    if (t < K) { bucket_off[t] = s[t] - v; bucket_cur[t] = s[t] - v; }
    if (t == K - 1) { bucket_off[K] = s[t]; row_start[N] = s[t]; }
}

__global__ __launch_bounds__(256) void k_binscatter(const int* __restrict__ src,
                                                    const int* __restrict__ dst,
                                                    int* bucket_cur, unsigned int* __restrict__ tmp,
                                                    int E, int N, int K) {
    __shared__ int h[4][512];
    int t = threadIdx.x, w = t >> 6;
    for (int i = t; i < 4 * 512; i += 256) ((int*)h)[i] = 0;
    __syncthreads();
    int per = (E + gridDim.x - 1) / gridDim.x;
    int lo = blockIdx.x * per, hi = min(lo + per, E);
    for (int e = lo + t; e < hi; e += 256) {
        unsigned int d = (unsigned int)dst[e];
        if (d < (unsigned int)N) atomicAdd(&h[w][d >> 8], 1);
    }
    __syncthreads();
    for (int k = t; k < K; k += 256) {
        int c0 = h[0][k], c1 = h[1][k], c2 = h[2][k], c3 = h[3][k];
        int tot = c0 + c1 + c2 + c3;
        int base = tot ? atomicAdd(&bucket_cur[k], tot) : 0;
        h[0][k] = base; h[1][k] = base + c0; h[2][k] = base + c0 + c1;
        h[3][k] = base + c0 + c1 + c2;
    }
    __syncthreads();
    for (int e = lo + t; e < hi; e += 256) {
        unsigned int d = (unsigned int)dst[e];
        if (d < (unsigned int)N) {
            unsigned int sv = (unsigned int)src[e];
            if (sv >= (unsigned int)N) sv = 0;
            int p = atomicAdd(&h[w][d >> 8], 1);
            tmp[p] = (sv << 8) | (d & 255u);
        }
    }
}

__global__ __launch_bounds__(256) void k_fine(const unsigned int* __restrict__ tmp,
                                              const int* __restrict__ bucket_off,
                                              int* __restrict__ row_start, float* __restrict__ dinv,
                                              int* __restrict__ csr, int N) {
    __shared__ int deg4[4][BK];
    __shared__ int scn[BK];
    __shared__ int cur[BK];
    int b = blockIdx.x, t = threadIdx.x, w = t >> 6;
    int lo = bucket_off[b], hi = bucket_off[b + 1];
    for (int i = t; i < 4 * BK; i += 256) ((int*)deg4)[i] = 0;
    __syncthreads();
    for (int e = lo + t; e < hi; e += 256) atomicAdd(&deg4[w][tmp[e] & 255u], 1);
    __syncthreads();
    int v = deg4[0][t] + deg4[1][t] + deg4[2][t] + deg4[3][t];
    scn[t] = v; __syncthreads();
    for (int off = 1; off < 256; off <<= 1) {
        int x = (t >= off) ? scn[t - off] : 0;
        __syncthreads();
        scn[t] += x;
        __syncthreads();
    }
    int rs = lo + scn[t] - v;
    cur[t] = rs;
    int node = b * BK + t;
    if (node < N) { row_start[node] = rs; dinv[node] = rsqrtf((float)(v + 1)); }
    __syncthreads();
    for (int e = lo + t; e < hi; e += 256) {
        unsigned int p = tmp[e];
        int pos = atomicAdd(&cur[p & 255u], 1);
        csr[pos] = (int)(p >> 8);
    }
}

// ---------------- GEMM: out[M,NOUT] = X[M,128] @ W[128,NOUT], K=128 ----------------
// SLICED layout = [8 slices][M nodes][16 ch] bf16 (slice-major; 32B per node-slice).
// XF32: X fp32 row-major. XSLICED: X bf16 sliced. OSLICED: out bf16 sliced.
// OUTF32: out fp32 row-major. Persistent: W staged in LDS once per block.

template <int NOUT, bool SCALE, bool BIAS, bool XF32, bool XSLICED, bool OUTF32, bool OSLICED>
__global__ __launch_bounds__(256, 2) void k_gemm(
    const void* __restrict__ Xv, const unsigned short* __restrict__ Wbf,
    const float* __restrict__ bias, const float* __restrict__ dinv,
    void* __restrict__ outv, int M, int MB) {
    // Wl[n*136 + k]; stride 136 (272B == 4 banks mod 32 -> 2-way conflict = free)
    __shared__ __align__(16) unsigned short Wl[NOUT * 136];
    int t = threadIdx.x;
    for (int c = t; c < NOUT * 16; c += 256) {
        short8 v = *(const short8*)(Wbf + (size_t)c * 8);
        *(short8*)(&Wl[(c >> 4) * 136 + (c & 15) * 8]) = v;
    }
    __syncthreads();

    int wave = t >> 6, lane = t & 63;
    int quad = lane >> 4, l16 = lane & 15;
    constexpr int NT = NOUT / 16;

    for (int mb = blockIdx.x; mb < MB; mb += gridDim.x) {
        int m0 = mb * 64 + wave * 16;
        int mr = m0 + l16;
        int mrc = mr < M ? mr : M - 1;

        floatx4 acc[NT];
#pragma unroll
        for (int i = 0; i < NT; i++) acc[i] = (floatx4){0.f, 0.f, 0.f, 0.f};

#pragma unroll
        for (int kc = 0; kc < 4; kc++) {
            short8 a;
            if (XF32) {
                const float* X = (const float*)Xv;
                const float* p = X + (size_t)mrc * 128 + kc * 32 + quad * 8;
                float4 xa = *(const float4*)p;
                float4 xb = *(const float4*)(p + 4);
                a[0] = (short)f2bf(xa.x); a[1] = (short)f2bf(xa.y);
                a[2] = (short)f2bf(xa.z); a[3] = (short)f2bf(xa.w);
                a[4] = (short)f2bf(xb.x); a[5] = (short)f2bf(xb.y);
                a[6] = (short)f2bf(xb.z); a[7] = (short)f2bf(xb.w);
            } else if (XSLICED) {
                const unsigned short* X = (const unsigned short*)Xv;
                int sl = kc * 2 + (quad >> 1);            // slice of channels kc*32+quad*8
                a = *(const short8*)(X + ((size_t)sl * M + mrc) * 16 + (quad & 1) * 8);
            } else {
                const unsigned short* X = (const unsigned short*)Xv;
                a = *(const short8*)(X + (size_t)mrc * 128 + kc * 32 + quad * 8);
            }
#pragma unroll
            for (int nt = 0; nt < NT; nt++) {
                short8 b = *(const short8*)(&Wl[(nt * 16 + l16) * 136 + kc * 32 + quad * 8]);
                acc[nt] = __builtin_amdgcn_mfma_f32_16x16x32_bf16(a, b, acc[nt], 0, 0, 0);
            }
        }

        // C layout: col = l16 (-> n = nt*16+l16), row (within 16) = quad*4 + i
#pragma unroll
        for (int i = 0; i < 4; i++) {
            int r = m0 + quad * 4 + i;
            if (r >= M) continue;
            float sc = SCALE ? dinv[r] : 1.0f;
#pragma unroll
            for (int nt = 0; nt < NT; nt++) {
                int n = nt * 16 + l16;
                float v = acc[nt][i] * sc;
                if (BIAS) v += bias[n];
                if (OUTF32) {
                    ((float*)outv)[(size_t)r * NOUT + n] = v;
                } else if (OSLICED) {
                    // n>>4 = nt, n&15 = l16
                    ((unsigned short*)outv)[((size_t)nt * M + r) * 16 + l16] = f2bf(v);
                } else {
                    ((unsigned short*)outv)[(size_t)r * NOUT + n] = f2bf(v);
                }
            }
        }
    }
}

// ---------------- Aggregation: XCD-sliced, L2-resident gathers ----------------
// out[d] = relu(dinv[d]*(H[d] + sum_nbr H[src]) + b), computed per 16-channel slice.
// H stored slice-major [8][N][16]: slice s = 3.2MB < 4MB per-XCD L2. Block handles
// ONE slice, s = blockIdx%8 -> MI355X round-robin dispatch pins slice s to XCD s,
// so every gather hits that XCD's L2 instead of the ~3.6 TB/s shared L3 random path
// (r0-r3: 187MB fills, insensitive to VALU/MLP -> fill-path bound).
// Wave = 4 nodes x 16 edge-lanes; lane owns one edge's full 32B slice (2 x uint4).
// NO shfl broadcast (each lane loads its own csr entry); only a 4-stage xor-reduce
// over the 16 edge-lanes, executed with all 64 lanes active (divergence-free).
// If the %8->XCD mapping assumption fails: working set reverts to 25.6MB -> perf
// matches the old kernel (~59us), no correctness impact.

__global__ __launch_bounds__(256, 8) void k_agg_slice(
    const unsigned short* __restrict__ Hs, const int* __restrict__ csr,
    const int* __restrict__ row_start, const float* __restrict__ dinv,
    const float* __restrict__ bias, unsigned short* __restrict__ out, int N, int E) {
    int s = blockIdx.x & 7, chunk = blockIdx.x >> 3;
    int t = threadIdx.x;
    int wave = t >> 6, lane = t & 63, sub = lane >> 4, el = lane & 15;
    int Nm1 = N - 1;
    const unsigned short* Hsl = Hs + (size_t)s * N * 16;
    unsigned short* Osl = out + (size_t)s * N * 16;

    // bias slice (16 ch), uniform per block
    const float* bsl = bias + s * 16;
    float4 q0 = *(const float4*)(bsl);
    float4 q1 = *(const float4*)(bsl + 4);
    float4 q2 = *(const float4*)(bsl + 8);
    float4 q3 = *(const float4*)(bsl + 12);

    int nb = chunk * 64 + wave * 16 + sub;   // pass p handles node nb + p*4
#pragma unroll 1
    for (int p = 0; p < 4; ++p) {
        int node = nb + p * 4;
        int node_c = node < N ? node : Nm1;
        int start = row_start[node_c];
        int end = row_start[node_c + 1];
        if (start < 0) start = 0;
        if (end > E) end = E;

        float a0 = 0.f, a1 = 0.f, a2 = 0.f, a3 = 0.f, a4 = 0.f, a5 = 0.f, a6 = 0.f, a7 = 0.f;
        float a8 = 0.f, a9 = 0.f, a10 = 0.f, a11 = 0.f, a12 = 0.f, a13 = 0.f, a14 = 0.f, a15 = 0.f;

        // avg degree 16 -> typically ONE iteration per lane
        for (int e = start + el; e < end; e += 16) {
            unsigned int ii = (unsigned int)csr[e];
            if (ii >= (unsigned int)N) ii = 0;
            const uint4* rp = (const uint4*)(Hsl + (size_t)ii * 16);
            uint4 ua = rp[0], ub = rp[1];
            a0 += bflo(ua.x); a1 += bfhi(ua.x); a2 += bflo(ua.y); a3 += bfhi(ua.y);
            a4 += bflo(ua.z); a5 += bfhi(ua.z); a6 += bflo(ua.w); a7 += bfhi(ua.w);
            a8 += bflo(ub.x); a9 += bfhi(ub.x); a10 += bflo(ub.y); a11 += bfhi(ub.y);
            a12 += bflo(ub.z); a13 += bfhi(ub.z); a14 += bflo(ub.w); a15 += bfhi(ub.w);
        }

        // reduce over the 16 edge-lanes (stays within each 16-lane group)
#define RED(W) \
        a0 += __shfl_xor(a0, W); a1 += __shfl_xor(a1, W); a2 += __shfl_xor(a2, W); \
        a3 += __shfl_xor(a3, W); a4 += __shfl_xor(a4, W); a5 += __shfl_xor(a5, W); \
        a6 += __shfl_xor(a6, W); a7 += __shfl_xor(a7, W); a8 += __shfl_xor(a8, W); \
        a9 += __shfl_xor(a9, W); a10 += __shfl_xor(a10, W); a11 += __shfl_xor(a11, W); \
        a12 += __shfl_xor(a12, W); a13 += __shfl_xor(a13, W); a14 += __shfl_xor(a14, W); \
        a15 += __shfl_xor(a15, W);
        RED(1) RED(2) RED(4) RED(8)
#undef RED

        if (el == 0 && node < N) {
            const uint4* sp = (const uint4*)(Hsl + (size_t)node * 16);
            uint4 sa = sp[0], sb = sp[1];
            a0 += bflo(sa.x); a1 += bfhi(sa.x); a2 += bflo(sa.y); a3 += bfhi(sa.y);
            a4 += bflo(sa.z); a5 += bfhi(sa.z); a6 += bflo(sa.w); a7 += bfhi(sa.w);
            a8 += bflo(sb.x); a9 += bfhi(sb.x); a10 += bflo(sb.y); a11 += bfhi(sb.y);
            a12 += bflo(sb.z); a13 += bfhi(sb.z); a14 += bflo(sb.w); a15 += bfhi(sb.w);
            float di = dinv[node];
            float r0 = fmaxf(fmaf(di, a0, q0.x), 0.f);
            float r1 = fmaxf(fmaf(di, a1, q0.y), 0.f);
            float r2 = fmaxf(fmaf(di, a2, q0.z), 0.f);
            float r3 = fmaxf(fmaf(di, a3, q0.w), 0.f);
            float r4 = fmaxf(fmaf(di, a4, q1.x), 0.f);
            float r5 = fmaxf(fmaf(di, a5, q1.y), 0.f);
            float r6 = fmaxf(fmaf(di, a6, q1.z), 0.f);
            float r7 = fmaxf(fmaf(di, a7, q1.w), 0.f);
            float r8 = fmaxf(fmaf(di, a8, q2.x), 0.f);
            float r9 = fmaxf(fmaf(di, a9, q2.y), 0.f);
            float r10 = fmaxf(fmaf(di, a10, q2.z), 0.f);
            float r11 = fmaxf(fmaf(di, a11, q2.w), 0.f);
            float r12 = fmaxf(fmaf(di, a12, q3.x), 0.f);
            float r13 = fmaxf(fmaf(di, a13, q3.y), 0.f);
            float r14 = fmaxf(fmaf(di, a14, q3.z), 0.f);
            float r15 = fmaxf(fmaf(di, a15, q3.w), 0.f);
            uint4 o0, o1;
            o0.x = (unsigned int)f2bf(r0) | ((unsigned int)f2bf(r1) << 16);
            o0.y = (unsigned int)f2bf(r2) | ((unsigned int)f2bf(r3) << 16);
            o0.z = (unsigned int)f2bf(r4) | ((unsigned int)f2bf(r5) << 16);
            o0.w = (unsigned int)f2bf(r6) | ((unsigned int)f2bf(r7) << 16);
            o1.x = (unsigned int)f2bf(r8) | ((unsigned int)f2bf(r9) << 16);
            o1.y = (unsigned int)f2bf(r10) | ((unsigned int)f2bf(r11) << 16);
            o1.z = (unsigned int)f2bf(r12) | ((unsigned int)f2bf(r13) << 16);
            o1.w = (unsigned int)f2bf(r14) | ((unsigned int)f2bf(r15) << 16);
            *(uint4*)(Osl + (size_t)node * 16) = o0;
            *(uint4*)(Osl + (size_t)node * 16 + 8) = o1;
        }
    }
}

// ---------------- launch ----------------

extern "C" void kernel_launch(void* const* d_in, const int* in_sizes, int n_in,
                              void* d_out, int out_size, void* d_ws, size_t ws_size,
                              hipStream_t stream) {
    const float* x  = (const float*)d_in[0];
    const int* ei   = (const int*)d_in[1];
    const float* W1 = (const float*)d_in[2];
    const float* b1 = (const float*)d_in[3];
    const float* W2 = (const float*)d_in[4];
    const float* b2 = (const float*)d_in[5];
    const float* Wf = (const float*)d_in[6];
    const float* bf = (const float*)d_in[7];

    int N = in_sizes[0] / 128;
    int E = in_sizes[1] / 2;
    const int* src = ei;
    const int* dst = ei + E;
    int K = (N + BK - 1) / BK;
    if (N >= (1 << 24) || K > 512) return;  // packing/scan assumptions

    size_t need = 0;
    auto pad = [](size_t b) { return (b + 255) & ~(size_t)255; };
    size_t o_bcnt = need; need += pad(512 * 4);
    size_t o_boff = need; need += pad(513 * 4);
    size_t o_bcur = need; need += pad(512 * 4);
    size_t o_rs   = need; need += pad(((size_t)N + 1) * 4);
    size_t o_dinv = need; need += pad((size_t)N * 4);
    size_t o_wbf  = need; need += pad((16384 + 16384 + 8192) * 2);
    size_t o_csr  = need; need += pad((size_t)E * 4);
    size_t o_hs   = need; need += pad((size_t)N * 128 * 2);
    size_t o_a    = need; need += pad((size_t)N * 128 * 2);
    if (ws_size < need) return;
    if ((size_t)E * 4 > (size_t)N * 128 * 2) return;  // tmp must fit in A alias

    char* ws = (char*)d_ws;
    int* bucket_cnt = (int*)(ws + o_bcnt);
    int* bucket_off = (int*)(ws + o_boff);
    int* bucket_cur = (int*)(ws + o_bcur);
    int* row_start  = (int*)(ws + o_rs);
    float* dinv     = (float*)(ws + o_dinv);
    unsigned short* wb1 = (unsigned short*)(ws + o_wbf);
    unsigned short* wb2 = wb1 + 16384;
    unsigned short* wbf = wb2 + 16384;
    int* csr        = (int*)(ws + o_csr);
    unsigned short* Hs = (unsigned short*)(ws + o_hs);   // sliced [8][N][16]
    unsigned short* A  = (unsigned short*)(ws + o_a);    // sliced [8][N][16]
    unsigned int* tmp  = (unsigned int*)A;  // alias: tmp dead before A's first write

    // ---- CSR build (5 launches, r3-proven) ----
    k_wconv_all<<<160, 256, 0, stream>>>(W1, W2, Wf, wb1, wb2, wbf, bucket_cnt);
    k_hist<<<256, 256, 0, stream>>>(dst, bucket_cnt, E, N, K);
    k_scanK<<<1, 512, 0, stream>>>(bucket_cnt, bucket_off, bucket_cur, row_start, K, N);
    k_binscatter<<<256, 256, 0, stream>>>(src, dst, bucket_cur, tmp, E, N, K);
    k_fine<<<K, 256, 0, stream>>>(tmp, bucket_off, row_start, dinv, csr, N);

    int MB = (N + 63) / 64;
    int GG = (MB + 1) / 2;       // persistent: 2 row-tiles per block
    int AGG = ((N + 63) / 64) * 8;  // 8 slice-blocks per 64-node chunk

    // layer 1: Hs(sliced) = dinv * (x @ W1)
    k_gemm<128, true, false, true, false, false, true><<<GG, 256, 0, stream>>>(
        x, wb1, nullptr, dinv, Hs, N, MB);
    // agg1: A(sliced) = relu(dinv*(Hs + sum Hs[src]) + b1)
    k_agg_slice<<<AGG, 256, 0, stream>>>(Hs, csr, row_start, dinv, b1, A, N, E);
    // layer 2: Hs(sliced) = dinv * (A @ W2)
    k_gemm<128, true, false, false, true, false, true><<<GG, 256, 0, stream>>>(
        A, wb2, nullptr, dinv, Hs, N, MB);
    // agg2: A(sliced) = relu(dinv*(Hs + sum Hs[src]) + b2)
    k_agg_slice<<<AGG, 256, 0, stream>>>(Hs, csr, row_start, dinv, b2, A, N, E);
    // final: out(fp32 row-major) = A @ Wf + bf
    k_gemm<64, false, true, false, true, true, false><<<GG, 256, 0, stream>>>(
        A, wbf, bf, nullptr, d_out, N, MB);
}

// Round 8
// 478.266 us; speedup vs baseline: 1.0152x; 1.0152x over previous
//
#include <hip/hip_runtime.h>
#include <stdint.h>

typedef short short8 __attribute__((ext_vector_type(8)));
typedef float floatx4 __attribute__((ext_vector_type(4)));
typedef float f32x2 __attribute__((ext_vector_type(2)));

#define BK 256   // nodes per bucket

static __device__ __forceinline__ float bflo(unsigned int u) {
    union { unsigned int i; float f; } v; v.i = u << 16; return v.f;
}
static __device__ __forceinline__ float bfhi(unsigned int u) {
    union { unsigned int i; float f; } v; v.i = u & 0xffff0000u; return v.f;
}
static __device__ __forceinline__ unsigned short f2bf(float f) {
    union { float f; unsigned int i; } v; v.f = f;
    unsigned int u = v.i;
    unsigned int r = u + 0x7fffu + ((u >> 16) & 1u);
    return (unsigned short)(r >> 16);
}
// unpack u32 (2 bf16) -> float2 {lo, hi}; feeds v_pk_add_f32
static __device__ __forceinline__ f32x2 unp2(unsigned int u) {
    union { unsigned int i; float f; } lo, hi;
    lo.i = u << 16; hi.i = u & 0xffff0000u;
    f32x2 r; r.x = lo.f; r.y = hi.f; return r;
}

// ---------------- CSR build (r3-proven chain; zero_cnt merged into wconv) ----------------
// r4: grid.sync ~50us/sync on MI355X -> multi-launch. r6: last-block hist+scan
// merge cost ~10us -> split hist/scanK kept.

__global__ void k_wconv_all(const float* __restrict__ W1, const float* __restrict__ W2,
                            const float* __restrict__ Wf, unsigned short* __restrict__ wb1,
                            unsigned short* __restrict__ wb2, unsigned short* __restrict__ wbf,
                            int* __restrict__ bucket_cnt) {
    int i = blockIdx.x * 256 + threadIdx.x;
    if (i < 512) bucket_cnt[i] = 0;
    if (i < 16384) {
        int k = i >> 7, n = i & 127;
        wb1[n * 128 + k] = f2bf(W1[i]);
    } else if (i < 32768) {
        int j = i - 16384, k = j >> 7, n = j & 127;
        wb2[n * 128 + k] = f2bf(W2[j]);
    } else if (i < 40960) {
        int j = i - 32768, k = j >> 6, n = j & 63;
        wbf[n * 128 + k] = f2bf(Wf[j]);
    }
}

__global__ __launch_bounds__(256) void k_hist(const int* __restrict__ dst, int* bucket_cnt,
                                              int E, int N, int K) {
    __shared__ int h[4][512];
    int t = threadIdx.x, w = t >> 6;
    for (int i = t; i < 4 * 512; i += 256) ((int*)h)[i] = 0;
    __syncthreads();
    int per = (E + gridDim.x - 1) / gridDim.x;
    int lo = blockIdx.x * per, hi = min(lo + per, E);
    for (int e = lo + t; e < hi; e += 256) {
        unsigned int d = (unsigned int)dst[e];
        if (d < (unsigned int)N) atomicAdd(&h[w][d >> 8], 1);
    }
    __syncthreads();
    for (int i = t; i < K; i += 256) {
        int c = h[0][i] + h[1][i] + h[2][i] + h[3][i];
        if (c) atomicAdd(&bucket_cnt[i], c);
    }
}

__global__ void k_scanK(const int* __restrict__ bucket_cnt, int* bucket_off, int* bucket_cur,
                        int* row_start, int K, int N) {
    __shared__ int s[512];
    int t = threadIdx.x;
    int v = (t < K) ? bucket_cnt[t] : 0;
    s[t] = v; __syncthreads();
    for (int off = 1; off < 512; off <<= 1) {
        int x = (t >= off) ? s[t - off] : 0;
        __syncthreads();
        s[t] += x;
        __syncthreads();
    }
    if (t < K) { bucket_off[t] = s[t] - v; bucket_cur[t] = s[t] - v; }
    if (t == K - 1) { bucket_off[K] = s[t]; row_start[N] = s[t]; }
}

__global__ __launch_bounds__(256) void k_binscatter(const int* __restrict__ src,
                                                    const int* __restrict__ dst,
                                                    int* bucket_cur, unsigned int* __restrict__ tmp,
                                                    int E, int N, int K) {
    __shared__ int h[4][512];
    int t = threadIdx.x, w = t >> 6;
    for (int i = t; i < 4 * 512; i += 256) ((int*)h)[i] = 0;
    __syncthreads();
    int per = (E + gridDim.x - 1) / gridDim.x;
    int lo = blockIdx.x * per, hi = min(lo + per, E);
    for (int e = lo + t; e < hi; e += 256) {
        unsigned int d = (unsigned int)dst[e];
        if (d < (unsigned int)N) atomicAdd(&h[w][d >> 8], 1);
    }
    __syncthreads();
    for (int k = t; k < K; k += 256) {
        int c0 = h[0][k], c1 = h[1][k], c2 = h[2][k], c3 = h[3][k];
        int tot = c0 + c1 + c2 + c3;
        int base = tot ? atomicAdd(&bucket_cur[k], tot) : 0;
        h[0][k] = base; h[1][k] = base + c0; h[2][k] = base + c0 + c1;
        h[3][k] = base + c0 + c1 + c2;
    }
    __syncthreads();
    for (int e = lo + t; e < hi; e += 256) {
        unsigned int d = (unsigned int)dst[e];
        if (d < (unsigned int)N) {
            unsigned int sv = (unsigned int)src[e];
            if (sv >= (unsigned int)N) sv = 0;
            int p = atomicAdd(&h[w][d >> 8], 1);
            tmp[p] = (sv << 8) | (d & 255u);
        }
    }
}

__global__ __launch_bounds__(256) void k_fine(const unsigned int* __restrict__ tmp,
                                              const int* __restrict__ bucket_off,
                                              int* __restrict__ row_start, float* __restrict__ dinv,
                                              int* __restrict__ csr, int N) {
    __shared__ int deg4[4][BK];
    __shared__ int scn[BK];
    __shared__ int cur[BK];
    int b = blockIdx.x, t = threadIdx.x, w = t >> 6;
    int lo = bucket_off[b], hi = bucket_off[b + 1];
    for (int i = t; i < 4 * BK; i += 256) ((int*)deg4)[i] = 0;
    __syncthreads();
    for (int e = lo + t; e < hi; e += 256) atomicAdd(&deg4[w][tmp[e] & 255u], 1);
    __syncthreads();
    int v = deg4[0][t] + deg4[1][t] + deg4[2][t] + deg4[3][t];
    scn[t] = v; __syncthreads();
    for (int off = 1; off < 256; off <<= 1) {
        int x = (t >= off) ? scn[t - off] : 0;
        __syncthreads();
        scn[t] += x;
        __syncthreads();
    }
    int rs = lo + scn[t] - v;
    cur[t] = rs;
    int node = b * BK + t;
    if (node < N) { row_start[node] = rs; dinv[node] = rsqrtf((float)(v + 1)); }
    __syncthreads();
    for (int e = lo + t; e < hi; e += 256) {
        unsigned int p = tmp[e];
        int pos = atomicAdd(&cur[p & 255u], 1);
        csr[pos] = (int)(p >> 8);
    }
}

// ---------------- GEMM: out[M,NOUT] = X[M,128] @ W[128,NOUT], K=128 ----------------
// SLICED layout = [8 slices][M nodes][16 ch] bf16 (slice-major; 32B per node-slice).
// XF32: X fp32 row-major. XSLICED: X bf16 sliced. OSLICED: out bf16 sliced.
// OUTF32: out fp32 row-major. Persistent: W staged in LDS once per block.
// (r7-verified, unchanged.)

template <int NOUT, bool SCALE, bool BIAS, bool XF32, bool XSLICED, bool OUTF32, bool OSLICED>
__global__ __launch_bounds__(256, 2) void k_gemm(
    const void* __restrict__ Xv, const unsigned short* __restrict__ Wbf,
    const float* __restrict__ bias, const float* __restrict__ dinv,
    void* __restrict__ outv, int M, int MB) {
    // Wl[n*136 + k]; stride 136 (272B == 4 banks mod 32 -> 2-way conflict = free)
    __shared__ __align__(16) unsigned short Wl[NOUT * 136];
    int t = threadIdx.x;
    for (int c = t; c < NOUT * 16; c += 256) {
        short8 v = *(const short8*)(Wbf + (size_t)c * 8);
        *(short8*)(&Wl[(c >> 4) * 136 + (c & 15) * 8]) = v;
    }
    __syncthreads();

    int wave = t >> 6, lane = t & 63;
    int quad = lane >> 4, l16 = lane & 15;
    constexpr int NT = NOUT / 16;

    for (int mb = blockIdx.x; mb < MB; mb += gridDim.x) {
        int m0 = mb * 64 + wave * 16;
        int mr = m0 + l16;
        int mrc = mr < M ? mr : M - 1;

        floatx4 acc[NT];
#pragma unroll
        for (int i = 0; i < NT; i++) acc[i] = (floatx4){0.f, 0.f, 0.f, 0.f};

#pragma unroll
        for (int kc = 0; kc < 4; kc++) {
            short8 a;
            if (XF32) {
                const float* X = (const float*)Xv;
                const float* p = X + (size_t)mrc * 128 + kc * 32 + quad * 8;
                float4 xa = *(const float4*)p;
                float4 xb = *(const float4*)(p + 4);
                a[0] = (short)f2bf(xa.x); a[1] = (short)f2bf(xa.y);
                a[2] = (short)f2bf(xa.z); a[3] = (short)f2bf(xa.w);
                a[4] = (short)f2bf(xb.x); a[5] = (short)f2bf(xb.y);
                a[6] = (short)f2bf(xb.z); a[7] = (short)f2bf(xb.w);
            } else if (XSLICED) {
                const unsigned short* X = (const unsigned short*)Xv;
                int sl = kc * 2 + (quad >> 1);            // slice of channels kc*32+quad*8
                a = *(const short8*)(X + ((size_t)sl * M + mrc) * 16 + (quad & 1) * 8);
            } else {
                const unsigned short* X = (const unsigned short*)Xv;
                a = *(const short8*)(X + (size_t)mrc * 128 + kc * 32 + quad * 8);
            }
#pragma unroll
            for (int nt = 0; nt < NT; nt++) {
                short8 b = *(const short8*)(&Wl[(nt * 16 + l16) * 136 + kc * 32 + quad * 8]);
                acc[nt] = __builtin_amdgcn_mfma_f32_16x16x32_bf16(a, b, acc[nt], 0, 0, 0);
            }
        }

        // C layout: col = l16 (-> n = nt*16+l16), row (within 16) = quad*4 + i
#pragma unroll
        for (int i = 0; i < 4; i++) {
            int r = m0 + quad * 4 + i;
            if (r >= M) continue;
            float sc = SCALE ? dinv[r] : 1.0f;
#pragma unroll
            for (int nt = 0; nt < NT; nt++) {
                int n = nt * 16 + l16;
                float v = acc[nt][i] * sc;
                if (BIAS) v += bias[n];
                if (OUTF32) {
                    ((float*)outv)[(size_t)r * NOUT + n] = v;
                } else if (OSLICED) {
                    // n>>4 = nt, n&15 = l16
                    ((unsigned short*)outv)[((size_t)nt * M + r) * 16 + l16] = f2bf(v);
                } else {
                    ((unsigned short*)outv)[(size_t)r * NOUT + n] = f2bf(v);
                }
            }
        }
    }
}

// ---------------- Aggregation: XCD-sliced + ONE LANE PER NODE ----------------
// r7 post-mortem: slicing WORKED (FETCH 187->57MB, gathers L2-resident) but the
// 16-lanes-per-node decomposition paid the reduce+epilogue 8x -> VALU blowup
// (64 shfl + 64 add per pass per slice; 151us at VALUBusy 64%).
// Fix: lane = node. Each lane walks its node's edge list, accumulating its
// 16-channel slice in 8 packed f32x2 regs. NO shfl, NO reduce, NO LDS; epilogue
// once per node per slice. 2-edge unroll -> 4 outstanding 16B gathers/lane.
// Stores coalesced (lane n -> node n, 32B stride). No shfl => early-return safe.
// Same slice->XCD mapping as r7 (blockIdx%8), proven by the FETCH drop.

__global__ __launch_bounds__(256, 8) void k_agg_node(
    const unsigned short* __restrict__ Hs, const int* __restrict__ csr,
    const int* __restrict__ row_start, const float* __restrict__ dinv,
    const float* __restrict__ bias, unsigned short* __restrict__ out, int N, int E) {
    int s = blockIdx.x & 7, chunk = blockIdx.x >> 3;
    int node = chunk * 256 + threadIdx.x;
    if (node >= N) return;                    // no cross-lane ops in this kernel
    const unsigned short* Hsl = Hs + (size_t)s * N * 16;
    unsigned short* Osl = out + (size_t)s * N * 16;

    int start = row_start[node];
    int end = row_start[node + 1];
    if (start < 0) start = 0;
    if (end > E) end = E;
    unsigned int Nu = (unsigned int)N;

    f32x2 c0 = {0.f, 0.f}, c1 = {0.f, 0.f}, c2 = {0.f, 0.f}, c3 = {0.f, 0.f};
    f32x2 c4 = {0.f, 0.f}, c5 = {0.f, 0.f}, c6 = {0.f, 0.f}, c7 = {0.f, 0.f};
#define ACCP(ua, ub) do { \
        c0 += unp2((ua).x); c1 += unp2((ua).y); c2 += unp2((ua).z); c3 += unp2((ua).w); \
        c4 += unp2((ub).x); c5 += unp2((ub).y); c6 += unp2((ub).z); c7 += unp2((ub).w); } while (0)

    int e = start;
    for (; e + 2 <= end; e += 2) {            // 2 edges/iter: 4 x 16B loads in flight
        unsigned int i0 = (unsigned int)csr[e];
        unsigned int i1 = (unsigned int)csr[e + 1];
        if (i0 >= Nu) i0 = 0;
        if (i1 >= Nu) i1 = 0;
        const uint4* p0 = (const uint4*)(Hsl + (size_t)i0 * 16);
        const uint4* p1 = (const uint4*)(Hsl + (size_t)i1 * 16);
        uint4 a0 = p0[0], b0 = p0[1];
        uint4 a1 = p1[0], b1 = p1[1];
        ACCP(a0, b0);
        ACCP(a1, b1);
    }
    if (e < end) {
        unsigned int i0 = (unsigned int)csr[e];
        if (i0 >= Nu) i0 = 0;
        const uint4* p0 = (const uint4*)(Hsl + (size_t)i0 * 16);
        uint4 a0 = p0[0], b0 = p0[1];
        ACCP(a0, b0);
    }
    // self-loop
    {
        const uint4* sp = (const uint4*)(Hsl + (size_t)node * 16);
        uint4 sa = sp[0], sb = sp[1];
        ACCP(sa, sb);
    }
#undef ACCP

    // epilogue: dinv scale + bias + relu, pack 16 bf16, one 32B store
    float di = dinv[node];
    const float* bsl = bias + s * 16;
    float4 q0 = *(const float4*)(bsl);
    float4 q1 = *(const float4*)(bsl + 4);
    float4 q2 = *(const float4*)(bsl + 8);
    float4 q3 = *(const float4*)(bsl + 12);
    float r0  = fmaxf(fmaf(di, c0.x, q0.x), 0.f);
    float r1  = fmaxf(fmaf(di, c0.y, q0.y), 0.f);
    float r2  = fmaxf(fmaf(di, c1.x, q0.z), 0.f);
    float r3  = fmaxf(fmaf(di, c1.y, q0.w), 0.f);
    float r4  = fmaxf(fmaf(di, c2.x, q1.x), 0.f);
    float r5  = fmaxf(fmaf(di, c2.y, q1.y), 0.f);
    float r6  = fmaxf(fmaf(di, c3.x, q1.z), 0.f);
    float r7  = fmaxf(fmaf(di, c3.y, q1.w), 0.f);
    float r8  = fmaxf(fmaf(di, c4.x, q2.x), 0.f);
    float r9  = fmaxf(fmaf(di, c4.y, q2.y), 0.f);
    float r10 = fmaxf(fmaf(di, c5.x, q2.z), 0.f);
    float r11 = fmaxf(fmaf(di, c5.y, q2.w), 0.f);
    float r12 = fmaxf(fmaf(di, c6.x, q3.x), 0.f);
    float r13 = fmaxf(fmaf(di, c6.y, q3.y), 0.f);
    float r14 = fmaxf(fmaf(di, c7.x, q3.z), 0.f);
    float r15 = fmaxf(fmaf(di, c7.y, q3.w), 0.f);
    uint4 o0, o1;
    o0.x = (unsigned int)f2bf(r0)  | ((unsigned int)f2bf(r1)  << 16);
    o0.y = (unsigned int)f2bf(r2)  | ((unsigned int)f2bf(r3)  << 16);
    o0.z = (unsigned int)f2bf(r4)  | ((unsigned int)f2bf(r5)  << 16);
    o0.w = (unsigned int)f2bf(r6)  | ((unsigned int)f2bf(r7)  << 16);
    o1.x = (unsigned int)f2bf(r8)  | ((unsigned int)f2bf(r9)  << 16);
    o1.y = (unsigned int)f2bf(r10) | ((unsigned int)f2bf(r11) << 16);
    o1.z = (unsigned int)f2bf(r12) | ((unsigned int)f2bf(r13) << 16);
    o1.w = (unsigned int)f2bf(r14) | ((unsigned int)f2bf(r15) << 16);
    *(uint4*)(Osl + (size_t)node * 16) = o0;
    *(uint4*)(Osl + (size_t)node * 16 + 8) = o1;
}

// ---------------- launch ----------------

extern "C" void kernel_launch(void* const* d_in, const int* in_sizes, int n_in,
                              void* d_out, int out_size, void* d_ws, size_t ws_size,
                              hipStream_t stream) {
    const float* x  = (const float*)d_in[0];
    const int* ei   = (const int*)d_in[1];
    const float* W1 = (const float*)d_in[2];
    const float* b1 = (const float*)d_in[3];
    const float* W2 = (const float*)d_in[4];
    const float* b2 = (const float*)d_in[5];
    const float* Wf = (const float*)d_in[6];
    const float* bf = (const float*)d_in[7];

    int N = in_sizes[0] / 128;
    int E = in_sizes[1] / 2;
    const int* src = ei;
    const int* dst = ei + E;
    int K = (N + BK - 1) / BK;
    if (N >= (1 << 24) || K > 512) return;  // packing/scan assumptions

    size_t need = 0;
    auto pad = [](size_t b) { return (b + 255) & ~(size_t)255; };
    size_t o_bcnt = need; need += pad(512 * 4);
    size_t o_boff = need; need += pad(513 * 4);
    size_t o_bcur = need; need += pad(512 * 4);
    size_t o_rs   = need; need += pad(((size_t)N + 1) * 4);
    size_t o_dinv = need; need += pad((size_t)N * 4);
    size_t o_wbf  = need; need += pad((16384 + 16384 + 8192) * 2);
    size_t o_csr  = need; need += pad((size_t)E * 4);
    size_t o_hs   = need; need += pad((size_t)N * 128 * 2);
    size_t o_a    = need; need += pad((size_t)N * 128 * 2);
    if (ws_size < need) return;
    if ((size_t)E * 4 > (size_t)N * 128 * 2) return;  // tmp must fit in A alias

    char* ws = (char*)d_ws;
    int* bucket_cnt = (int*)(ws + o_bcnt);
    int* bucket_off = (int*)(ws + o_boff);
    int* bucket_cur = (int*)(ws + o_bcur);
    int* row_start  = (int*)(ws + o_rs);
    float* dinv     = (float*)(ws + o_dinv);
    unsigned short* wb1 = (unsigned short*)(ws + o_wbf);
    unsigned short* wb2 = wb1 + 16384;
    unsigned short* wbf = wb2 + 16384;
    int* csr        = (int*)(ws + o_csr);
    unsigned short* Hs = (unsigned short*)(ws + o_hs);   // sliced [8][N][16]
    unsigned short* A  = (unsigned short*)(ws + o_a);    // sliced [8][N][16]
    unsigned int* tmp  = (unsigned int*)A;  // alias: tmp dead before A's first write

    // ---- CSR build (5 launches, r3-proven) ----
    k_wconv_all<<<160, 256, 0, stream>>>(W1, W2, Wf, wb1, wb2, wbf, bucket_cnt);
    k_hist<<<256, 256, 0, stream>>>(dst, bucket_cnt, E, N, K);
    k_scanK<<<1, 512, 0, stream>>>(bucket_cnt, bucket_off, bucket_cur, row_start, K, N);
    k_binscatter<<<256, 256, 0, stream>>>(src, dst, bucket_cur, tmp, E, N, K);
    k_fine<<<K, 256, 0, stream>>>(tmp, bucket_off, row_start, dinv, csr, N);

    int MB = (N + 63) / 64;
    int GG = (MB + 1) / 2;          // persistent: 2 row-tiles per block
    int AGG = ((N + 255) / 256) * 8;  // 8 slice-blocks per 256-node chunk

    // layer 1: Hs(sliced) = dinv * (x @ W1)
    k_gemm<128, true, false, true, false, false, true><<<GG, 256, 0, stream>>>(
        x, wb1, nullptr, dinv, Hs, N, MB);
    // agg1: A(sliced) = relu(dinv*(Hs + sum Hs[src]) + b1)
    k_agg_node<<<AGG, 256, 0, stream>>>(Hs, csr, row_start, dinv, b1, A, N, E);
    // layer 2: Hs(sliced) = dinv * (A @ W2)
    k_gemm<128, true, false, false, true, false, true><<<GG, 256, 0, stream>>>(
        A, wb2, nullptr, dinv, Hs, N, MB);
    // agg2: A(sliced) = relu(dinv*(Hs + sum Hs[src]) + b2)
    k_agg_node<<<AGG, 256, 0, stream>>>(Hs, csr, row_start, dinv, b2, A, N, E);
    // final: out(fp32 row-major) = A @ Wf + bf
    k_gemm<64, false, true, false, true, true, false><<<GG, 256, 0, stream>>>(
        A, wbf, bf, nullptr, d_out, N, MB);
}